// Round 10
// baseline (322.830 us; speedup 1.0000x reference)
//
#include <hip/hip_runtime.h>
#include <hip/hip_bf16.h>

// B=16, S=512, D=64, V=32000.
// embed(norm) -> unnormalized-exp dist attn (+ invsum) -> 2x prop(fold invsum*scale)
// -> logits = h2 @ out_w^T (bf16 MFMA, f32 accum).
// Logits: streaming 128row x 512col tile; LDS epilogue drains each row as TWO
// back-to-back 1KB store instructions (2KB sequential per wave-row).
// Grid 64mt x 63nt: 62 full 512-col panels + 1 tail 256-col panel (guarded).

#define S_ 512
#define D_ 64
#define V_ 32000

typedef __attribute__((ext_vector_type(8))) __bf16 bf16x8;
typedef __attribute__((ext_vector_type(4))) float f32x4;

__device__ inline unsigned short f2bf(float x) {
    __hip_bfloat16 h = __float2bfloat16(x);
    return __builtin_bit_cast(unsigned short, h);
}

// ---------------- embed: emb[row][d], n2[row] ----------------
__global__ __launch_bounds__(256) void embed_kernel(const int* __restrict__ tokens,
                                                    const float* __restrict__ temb,
                                                    float* __restrict__ emb,
                                                    float* __restrict__ n2) {
    int row  = blockIdx.x * 4 + (threadIdx.x >> 6);
    int lane = threadIdx.x & 63;
    int s    = row & (S_ - 1);
    int tok  = tokens[row];
    float val;
    if (lane < 2) {
        float fs    = (float)s;
        float theta = 6.283185307179586f * (fs * (1.0f / 512.0f));
        float r     = 0.3f + 0.6f * (fs * (1.0f / 511.0f));
        val = (lane == 0) ? r * cosf(theta) : r * sinf(theta);
    } else {
        val = temb[tok * D_ + lane - 2];
    }
    float ss = val * val;
#pragma unroll
    for (int off = 32; off; off >>= 1) ss += __shfl_xor(ss, off, 64);
    float nrm = sqrtf(fmaxf(ss, 1e-12f));
    float e   = val / nrm;
    emb[row * D_ + lane] = e;
    float nn = e * e;
#pragma unroll
    for (int off = 32; off; off >>= 1) nn += __shfl_xor(nn, off, 64);
    if (lane == 0) n2[row] = nn;
}

// ------- attention: attn_u[b][q][k] = exp(-dist) (unnorm), invs = scale/rowsum ----
__global__ __launch_bounds__(128) void attn_kernel(const float* __restrict__ emb,
                                                   const float* __restrict__ n2,
                                                   const float* __restrict__ edge_scale,
                                                   float* __restrict__ attn_u,
                                                   float* __restrict__ invs) {
    __shared__ float qs[16][68];
    __shared__ float ks[64][68];
    __shared__ float n2qs[16];
    __shared__ float n2ks[64];
    int b  = blockIdx.x >> 5;
    int q0 = (blockIdx.x & 31) * 16;
    int t  = threadIdx.x;           // 0..127
    const float* ebase = emb + (size_t)b * S_ * D_;
#pragma unroll
    for (int j = 0; j < 2; ++j) {   // qs: 16x64 = 256 f32x4
        int f4 = t + j * 128;
        int r = f4 >> 4, c4 = (f4 & 15) * 4;
        *reinterpret_cast<float4*>(&qs[r][c4]) =
            *reinterpret_cast<const float4*>(&ebase[(q0 + r) * D_ + c4]);
    }
    if (t < 16) n2qs[t] = n2[b * S_ + q0 + t];

    int qg = t >> 4;   // 0..7 -> q rows qg*2+i
    int kg = t & 15;   // k cols kg*4+j
    float rs[2] = {0.f, 0.f};

    for (int kt = 0; kt < 8; ++kt) {
        int k0 = kt * 64;
        __syncthreads();
#pragma unroll
        for (int j = 0; j < 8; ++j) {   // ks: 64x64 = 1024 f32x4
            int f4 = t + j * 128;
            int r = f4 >> 4, c4 = (f4 & 15) * 4;
            *reinterpret_cast<float4*>(&ks[r][c4]) =
                *reinterpret_cast<const float4*>(&ebase[(k0 + r) * D_ + c4]);
        }
        if (t < 64) n2ks[t] = n2[b * S_ + k0 + t];
        __syncthreads();

        f32x4 acc[2][4];
#pragma unroll
        for (int i = 0; i < 2; ++i)
#pragma unroll
            for (int j = 0; j < 4; ++j) acc[i][j] = (f32x4){0.f, 0.f, 0.f, 0.f};
#pragma unroll
        for (int dc = 0; dc < 16; ++dc) {
            f32x4 qv[2], kv[4];
#pragma unroll
            for (int i = 0; i < 2; ++i) qv[i] = *reinterpret_cast<f32x4*>(&qs[qg * 2 + i][dc * 4]);
#pragma unroll
            for (int j = 0; j < 4; ++j) kv[j] = *reinterpret_cast<f32x4*>(&ks[kg * 4 + j][dc * 4]);
#pragma unroll
            for (int i = 0; i < 2; ++i)
#pragma unroll
                for (int j = 0; j < 4; ++j) acc[i][j] += qv[i] * kv[j];
        }
#pragma unroll
        for (int i = 0; i < 2; ++i) {
            int q = qg * 2 + i;
            float4 ev;
            float* evp = &ev.x;
#pragma unroll
            for (int j = 0; j < 4; ++j) {
                int k = kg * 4 + j;
                f32x4 a = acc[i][j];
                float dot = (a[0] + a[1]) + (a[2] + a[3]);
                float sq  = n2qs[q] + n2ks[k] - 2.0f * dot;
                evp[j] = (q0 + q == k0 + k) ? 1.0f : expf(-sqrtf(fmaxf(sq, 1e-12f)));
            }
            rs[i] += (ev.x + ev.y) + (ev.z + ev.w);
            *reinterpret_cast<float4*>(
                &attn_u[((size_t)(b * S_ + q0 + q)) * S_ + k0 + kg * 4]) = ev;
        }
    }
    float scale = edge_scale[0];
#pragma unroll
    for (int i = 0; i < 2; ++i) {
#pragma unroll
        for (int off = 1; off < 16; off <<= 1) rs[i] += __shfl_xor(rs[i], off, 64);
        if (kg == 0) invs[b * S_ + q0 + qg * 2 + i] = scale / rs[i];
    }
}

// ---------------- proj: out = h @ w^T  (16 rows/block, e-vectorized) ----------------
__global__ __launch_bounds__(256) void proj_kernel(const float* __restrict__ h,
                                                   const float* __restrict__ w,
                                                   float* __restrict__ out) {
    __shared__ float ws[64][68];
    __shared__ float hs[16][68];
    int t  = threadIdx.x;
    int r0 = blockIdx.x * 16;
#pragma unroll
    for (int j = 0; j < 4; ++j) {
        int f4 = t + j * 256;
        int r = f4 >> 4, c4 = (f4 & 15) * 4;
        *reinterpret_cast<float4*>(&ws[r][c4]) =
            *reinterpret_cast<const float4*>(&w[r * D_ + c4]);
    }
    {
        int r = t >> 4, c4 = (t & 15) * 4;
        *reinterpret_cast<float4*>(&hs[r][c4]) =
            *reinterpret_cast<const float4*>(&h[(r0 + r) * D_ + c4]);
    }
    __syncthreads();
    int q = t >> 4, dh = t & 15;
    f32x4 acc[4];
#pragma unroll
    for (int dj = 0; dj < 4; ++dj) acc[dj] = (f32x4){0.f, 0.f, 0.f, 0.f};
#pragma unroll
    for (int ec = 0; ec < 16; ++ec) {
        f32x4 hv = *reinterpret_cast<f32x4*>(&hs[q][ec * 4]);
#pragma unroll
        for (int dj = 0; dj < 4; ++dj) {
            f32x4 wv = *reinterpret_cast<f32x4*>(&ws[dh * 4 + dj][ec * 4]);
            acc[dj] += hv * wv;
        }
    }
    float4 r;
    r.x = (acc[0][0] + acc[0][1]) + (acc[0][2] + acc[0][3]);
    r.y = (acc[1][0] + acc[1][1]) + (acc[1][2] + acc[1][3]);
    r.z = (acc[2][0] + acc[2][1]) + (acc[2][2] + acc[2][3]);
    r.w = (acc[3][0] + acc[3][1]) + (acc[3][2] + acc[3][3]);
    *reinterpret_cast<float4*>(&out[(r0 + q) * D_ + dh * 4]) = r;
}

// ------- prop: out = invs[q] * (attn_u @ t)  (16q/block, 2q x 4d per thread) --------
template <bool BF16OUT>
__global__ __launch_bounds__(128) void prop_kernel(const float* __restrict__ attn_u,
                                                   const float* __restrict__ tmat,
                                                   const float* __restrict__ invs,
                                                   float* __restrict__ outf,
                                                   unsigned short* __restrict__ outb) {
    __shared__ float As[16][68];
    __shared__ float Ts[64][68];
    int b  = blockIdx.x >> 5;
    int q0 = (blockIdx.x & 31) * 16;
    int t  = threadIdx.x;           // 0..127
    int qg = t >> 4, dh = t & 15;
    f32x4 acc[2];
#pragma unroll
    for (int i = 0; i < 2; ++i) acc[i] = (f32x4){0.f, 0.f, 0.f, 0.f};
    const float* abase = attn_u + ((size_t)b * S_ + q0) * S_;
    const float* tbase = tmat + (size_t)b * S_ * D_;
    for (int kt = 0; kt < 8; ++kt) {
        int k0 = kt * 64;
        __syncthreads();
#pragma unroll
        for (int j = 0; j < 2; ++j) {
            int f4 = t + j * 128;
            int r = f4 >> 4, c4 = (f4 & 15) * 4;
            *reinterpret_cast<float4*>(&As[r][c4]) =
                *reinterpret_cast<const float4*>(&abase[(size_t)r * S_ + k0 + c4]);
        }
#pragma unroll
        for (int j = 0; j < 8; ++j) {
            int f4 = t + j * 128;
            int r = f4 >> 4, c4 = (f4 & 15) * 4;
            *reinterpret_cast<float4*>(&Ts[r][c4]) =
                *reinterpret_cast<const float4*>(&tbase[(k0 + r) * D_ + c4]);
        }
        __syncthreads();
#pragma unroll
        for (int kc = 0; kc < 16; ++kc) {
            f32x4 tv[4];
#pragma unroll
            for (int ks = 0; ks < 4; ++ks)
                tv[ks] = *reinterpret_cast<f32x4*>(&Ts[kc * 4 + ks][dh * 4]);
#pragma unroll
            for (int i = 0; i < 2; ++i) {
                f32x4 av = *reinterpret_cast<f32x4*>(&As[qg * 2 + i][kc * 4]);
#pragma unroll
                for (int ks = 0; ks < 4; ++ks) acc[i] += av[ks] * tv[ks];
            }
        }
    }
#pragma unroll
    for (int i = 0; i < 2; ++i) {
        int row = b * S_ + q0 + qg * 2 + i;
        float inv = invs[row];
        size_t rowbase = (size_t)row * D_ + dh * 4;
        if (BF16OUT) {
            ushort4 r;
            r.x = f2bf(inv * acc[i][0]); r.y = f2bf(inv * acc[i][1]);
            r.z = f2bf(inv * acc[i][2]); r.w = f2bf(inv * acc[i][3]);
            *reinterpret_cast<ushort4*>(&outb[rowbase]) = r;
        } else {
            *reinterpret_cast<float4*>(&outf[rowbase]) =
                make_float4(inv * acc[i][0], inv * acc[i][1],
                            inv * acc[i][2], inv * acc[i][3]);
        }
    }
}

// ---------------- f32 -> bf16 cast (out_w) ----------------
__global__ __launch_bounds__(256) void cast_kernel(const float* __restrict__ in,
                                                   unsigned short* __restrict__ out, int n) {
    int i = (blockIdx.x * 256 + threadIdx.x) * 4;
    if (i >= n) return;
    float4 v = *reinterpret_cast<const float4*>(in + i);
    ushort4 r;
    r.x = f2bf(v.x); r.y = f2bf(v.y); r.z = f2bf(v.z); r.w = f2bf(v.w);
    *reinterpret_cast<ushort4*>(out + i) = r;
}

// ---------------- logits: out[8192,32000] = h2 @ out_w^T  (bf16 MFMA) ----------------
// 128 rows x 512 cols per block; grid 4032 = 64 mt x 63 nt (last panel 256-wide,
// second 1KB segment guarded off). Streaming per-16-rows; single-buffer 33KB LDS,
// 4 blocks/CU; drain = 2 consecutive 1KB store instrs per row (2KB sequential).
__global__ __launch_bounds__(256, 4) void logits_kernel(const unsigned short* __restrict__ hb,
                                                        const unsigned short* __restrict__ wb,
                                                        float* __restrict__ out) {
    __shared__ float Ct[16][516];
    int bid = blockIdx.x;
    int nt = bid % 63, mt = bid / 63;
    int n0 = nt * 512, m0 = mt * 128;
    int wave = threadIdx.x >> 6, lane = threadIdx.x & 63;
    int lr = lane & 15, lh = lane >> 4;
    int cbase = wave * 128;   // this wave's 128-col sub-panel

    // a-frags: 8 ns x 2 kh. For the tail panel (nt==62) rows >=32000 read into the
    // allocated n2/invs tail of d_ws (<=32KB past wb) — computed but never stored.
    bf16x8 a[8][2];
#pragma unroll
    for (int ns = 0; ns < 8; ++ns)
#pragma unroll
        for (int kh = 0; kh < 2; ++kh)
            a[ns][kh] = *reinterpret_cast<const bf16x8*>(
                wb + (size_t)(n0 + cbase + ns * 16 + lr) * D_ + kh * 32 + lh * 8);

    for (int ms = 0; ms < 8; ++ms) {
        const unsigned short* hrow = hb + (size_t)(m0 + ms * 16 + lr) * D_ + lh * 8;
        bf16x8 b0 = *reinterpret_cast<const bf16x8*>(hrow);
        bf16x8 b1 = *reinterpret_cast<const bf16x8*>(hrow + 32);

        f32x4 acc[8];
#pragma unroll
        for (int ns = 0; ns < 8; ++ns) {
            acc[ns] = (f32x4){0.f, 0.f, 0.f, 0.f};
            acc[ns] = __builtin_amdgcn_mfma_f32_16x16x32_bf16(a[ns][0], b0, acc[ns], 0, 0, 0);
            acc[ns] = __builtin_amdgcn_mfma_f32_16x16x32_bf16(a[ns][1], b1, acc[ns], 0, 0, 0);
        }

        // stage: row lr, col cbase + ns*16 + lh*4
#pragma unroll
        for (int ns = 0; ns < 8; ++ns) {
            f32x4 v = acc[ns];
            *reinterpret_cast<float4*>(&Ct[lr][cbase + ns * 16 + lh * 4]) =
                make_float4(v[0], v[1], v[2], v[3]);
        }
        __syncthreads();

        // drain: wave owns rows wave*4..wave*4+3; per row, 2 consecutive 1KB stores
#pragma unroll
        for (int j = 0; j < 4; ++j) {
            int row = wave * 4 + j;
            size_t gbase = (size_t)(m0 + ms * 16 + row) * V_ + n0;
#pragma unroll
            for (int s = 0; s < 2; ++s) {
                if (n0 + s * 256 < V_) {   // uniform guard (tail panel skips s=1)
                    const float* Lr = &Ct[row][s * 256 + lane * 4];
                    float4 v = *reinterpret_cast<const float4*>(Lr);
                    *reinterpret_cast<float4*>(out + gbase + s * 256 + lane * 4) = v;
                }
            }
        }
        __syncthreads();
    }
}

extern "C" void kernel_launch(void* const* d_in, const int* in_sizes, int n_in,
                              void* d_out, int out_size, void* d_ws, size_t ws_size,
                              hipStream_t stream) {
    const int*   tokens = (const int*)d_in[0];
    const float* temb   = (const float*)d_in[1];
    const float* w1     = (const float*)d_in[2];
    const float* w2     = (const float*)d_in[3];
    const float* escale = (const float*)d_in[4];
    const float* outw   = (const float*)d_in[5];
    float*       out    = (float*)d_out;

    // Large scratch in tail of d_out (1,048,576,000 B); consumed before logits.
    char* tail = (char*)d_out + 1048576000ull - 23068672ull;
    float* attn = (float*)(tail);                   // 16 MB (unnormalized exp)
    float* emb  = (float*)(tail + 16777216);        // 2 MB
    float* t1   = (float*)(tail + 18874368);        // 2 MB
    float* h1   = (float*)(tail + 20971520);        // 2 MB (ends at out end)

    // Small scratch in d_ws (~5.25 MB).
    char* ws = (char*)d_ws;
    unsigned short* hb   = (unsigned short*)(ws);             // 1 MB
    unsigned short* wb   = (unsigned short*)(ws + 1048576);   // 4 MB
    float*          n2   = (float*)(ws + 5144576);            // 32 KB
    float*          invs = (float*)(ws + 5177344);            // 32 KB

    embed_kernel<<<2048, 256, 0, stream>>>(tokens, temb, emb, n2);
    attn_kernel<<<512, 128, 0, stream>>>(emb, n2, escale, attn, invs);
    cast_kernel<<<2000, 256, 0, stream>>>(outw, wb, V_ * D_);
    proj_kernel<<<512, 256, 0, stream>>>(emb, w1, t1);
    prop_kernel<false><<<512, 128, 0, stream>>>(attn, t1, invs, h1, nullptr);
    proj_kernel<<<512, 256, 0, stream>>>(h1, w2, t1);
    prop_kernel<true><<<512, 128, 0, stream>>>(attn, t1, invs, nullptr, hb);
    logits_kernel<<<4032, 256, 0, stream>>>(hb, wb, out);
}

// Round 11
// 290.880 us; speedup vs baseline: 1.1098x; 1.1098x over previous
//
#include <hip/hip_runtime.h>
#include <hip/hip_bf16.h>

// B=16, S=512, D=64, V=32000.
// embed(norm) -> unnormalized-exp dist attn (+ invsum) -> 2x prop(fold invsum*scale)
// -> logits = h2 @ out_w^T (bf16 MFMA, f32 accum).
// Logits: r9's proven-best 128x256 streaming tile, dbuf LDS epilogue, 1KB/instr
// drain — with the redundant trailing barrier removed (dbuf makes it safe).

#define S_ 512
#define D_ 64
#define V_ 32000

typedef __attribute__((ext_vector_type(8))) __bf16 bf16x8;
typedef __attribute__((ext_vector_type(4))) float f32x4;

__device__ inline unsigned short f2bf(float x) {
    __hip_bfloat16 h = __float2bfloat16(x);
    return __builtin_bit_cast(unsigned short, h);
}

// ---------------- embed: emb[row][d], n2[row] ----------------
__global__ __launch_bounds__(256) void embed_kernel(const int* __restrict__ tokens,
                                                    const float* __restrict__ temb,
                                                    float* __restrict__ emb,
                                                    float* __restrict__ n2) {
    int row  = blockIdx.x * 4 + (threadIdx.x >> 6);
    int lane = threadIdx.x & 63;
    int s    = row & (S_ - 1);
    int tok  = tokens[row];
    float val;
    if (lane < 2) {
        float fs    = (float)s;
        float theta = 6.283185307179586f * (fs * (1.0f / 512.0f));
        float r     = 0.3f + 0.6f * (fs * (1.0f / 511.0f));
        val = (lane == 0) ? r * cosf(theta) : r * sinf(theta);
    } else {
        val = temb[tok * D_ + lane - 2];
    }
    float ss = val * val;
#pragma unroll
    for (int off = 32; off; off >>= 1) ss += __shfl_xor(ss, off, 64);
    float nrm = sqrtf(fmaxf(ss, 1e-12f));
    float e   = val / nrm;
    emb[row * D_ + lane] = e;
    float nn = e * e;
#pragma unroll
    for (int off = 32; off; off >>= 1) nn += __shfl_xor(nn, off, 64);
    if (lane == 0) n2[row] = nn;
}

// ------- attention: attn_u[b][q][k] = exp(-dist) (unnorm), invs = scale/rowsum ----
__global__ __launch_bounds__(128) void attn_kernel(const float* __restrict__ emb,
                                                   const float* __restrict__ n2,
                                                   const float* __restrict__ edge_scale,
                                                   float* __restrict__ attn_u,
                                                   float* __restrict__ invs) {
    __shared__ float qs[16][68];
    __shared__ float ks[64][68];
    __shared__ float n2qs[16];
    __shared__ float n2ks[64];
    int b  = blockIdx.x >> 5;
    int q0 = (blockIdx.x & 31) * 16;
    int t  = threadIdx.x;           // 0..127
    const float* ebase = emb + (size_t)b * S_ * D_;
#pragma unroll
    for (int j = 0; j < 2; ++j) {   // qs: 16x64 = 256 f32x4
        int f4 = t + j * 128;
        int r = f4 >> 4, c4 = (f4 & 15) * 4;
        *reinterpret_cast<float4*>(&qs[r][c4]) =
            *reinterpret_cast<const float4*>(&ebase[(q0 + r) * D_ + c4]);
    }
    if (t < 16) n2qs[t] = n2[b * S_ + q0 + t];

    int qg = t >> 4;   // 0..7 -> q rows qg*2+i
    int kg = t & 15;   // k cols kg*4+j
    float rs[2] = {0.f, 0.f};

    for (int kt = 0; kt < 8; ++kt) {
        int k0 = kt * 64;
        __syncthreads();
#pragma unroll
        for (int j = 0; j < 8; ++j) {   // ks: 64x64 = 1024 f32x4
            int f4 = t + j * 128;
            int r = f4 >> 4, c4 = (f4 & 15) * 4;
            *reinterpret_cast<float4*>(&ks[r][c4]) =
                *reinterpret_cast<const float4*>(&ebase[(k0 + r) * D_ + c4]);
        }
        if (t < 64) n2ks[t] = n2[b * S_ + k0 + t];
        __syncthreads();

        f32x4 acc[2][4];
#pragma unroll
        for (int i = 0; i < 2; ++i)
#pragma unroll
            for (int j = 0; j < 4; ++j) acc[i][j] = (f32x4){0.f, 0.f, 0.f, 0.f};
#pragma unroll
        for (int dc = 0; dc < 16; ++dc) {
            f32x4 qv[2], kv[4];
#pragma unroll
            for (int i = 0; i < 2; ++i) qv[i] = *reinterpret_cast<f32x4*>(&qs[qg * 2 + i][dc * 4]);
#pragma unroll
            for (int j = 0; j < 4; ++j) kv[j] = *reinterpret_cast<f32x4*>(&ks[kg * 4 + j][dc * 4]);
#pragma unroll
            for (int i = 0; i < 2; ++i)
#pragma unroll
                for (int j = 0; j < 4; ++j) acc[i][j] += qv[i] * kv[j];
        }
#pragma unroll
        for (int i = 0; i < 2; ++i) {
            int q = qg * 2 + i;
            float4 ev;
            float* evp = &ev.x;
#pragma unroll
            for (int j = 0; j < 4; ++j) {
                int k = kg * 4 + j;
                f32x4 a = acc[i][j];
                float dot = (a[0] + a[1]) + (a[2] + a[3]);
                float sq  = n2qs[q] + n2ks[k] - 2.0f * dot;
                evp[j] = (q0 + q == k0 + k) ? 1.0f : __expf(-sqrtf(fmaxf(sq, 1e-12f)));
            }
            rs[i] += (ev.x + ev.y) + (ev.z + ev.w);
            *reinterpret_cast<float4*>(
                &attn_u[((size_t)(b * S_ + q0 + q)) * S_ + k0 + kg * 4]) = ev;
        }
    }
    float scale = edge_scale[0];
#pragma unroll
    for (int i = 0; i < 2; ++i) {
#pragma unroll
        for (int off = 1; off < 16; off <<= 1) rs[i] += __shfl_xor(rs[i], off, 64);
        if (kg == 0) invs[b * S_ + q0 + qg * 2 + i] = scale / rs[i];
    }
}

// ---------------- proj: out = h @ w^T  (16 rows/block, e-vectorized) ----------------
__global__ __launch_bounds__(256) void proj_kernel(const float* __restrict__ h,
                                                   const float* __restrict__ w,
                                                   float* __restrict__ out) {
    __shared__ float ws[64][68];
    __shared__ float hs[16][68];
    int t  = threadIdx.x;
    int r0 = blockIdx.x * 16;
#pragma unroll
    for (int j = 0; j < 4; ++j) {
        int f4 = t + j * 256;
        int r = f4 >> 4, c4 = (f4 & 15) * 4;
        *reinterpret_cast<float4*>(&ws[r][c4]) =
            *reinterpret_cast<const float4*>(&w[r * D_ + c4]);
    }
    {
        int r = t >> 4, c4 = (t & 15) * 4;
        *reinterpret_cast<float4*>(&hs[r][c4]) =
            *reinterpret_cast<const float4*>(&h[(r0 + r) * D_ + c4]);
    }
    __syncthreads();
    int q = t >> 4, dh = t & 15;
    f32x4 acc[4];
#pragma unroll
    for (int dj = 0; dj < 4; ++dj) acc[dj] = (f32x4){0.f, 0.f, 0.f, 0.f};
#pragma unroll
    for (int ec = 0; ec < 16; ++ec) {
        f32x4 hv = *reinterpret_cast<f32x4*>(&hs[q][ec * 4]);
#pragma unroll
        for (int dj = 0; dj < 4; ++dj) {
            f32x4 wv = *reinterpret_cast<f32x4*>(&ws[dh * 4 + dj][ec * 4]);
            acc[dj] += hv * wv;
        }
    }
    float4 r;
    r.x = (acc[0][0] + acc[0][1]) + (acc[0][2] + acc[0][3]);
    r.y = (acc[1][0] + acc[1][1]) + (acc[1][2] + acc[1][3]);
    r.z = (acc[2][0] + acc[2][1]) + (acc[2][2] + acc[2][3]);
    r.w = (acc[3][0] + acc[3][1]) + (acc[3][2] + acc[3][3]);
    *reinterpret_cast<float4*>(&out[(r0 + q) * D_ + dh * 4]) = r;
}

// ------- prop: out = invs[q] * (attn_u @ t)  (16q/block, 2q x 4d per thread) --------
template <bool BF16OUT>
__global__ __launch_bounds__(128) void prop_kernel(const float* __restrict__ attn_u,
                                                   const float* __restrict__ tmat,
                                                   const float* __restrict__ invs,
                                                   float* __restrict__ outf,
                                                   unsigned short* __restrict__ outb) {
    __shared__ float As[16][68];
    __shared__ float Ts[64][68];
    int b  = blockIdx.x >> 5;
    int q0 = (blockIdx.x & 31) * 16;
    int t  = threadIdx.x;           // 0..127
    int qg = t >> 4, dh = t & 15;
    f32x4 acc[2];
#pragma unroll
    for (int i = 0; i < 2; ++i) acc[i] = (f32x4){0.f, 0.f, 0.f, 0.f};
    const float* abase = attn_u + ((size_t)b * S_ + q0) * S_;
    const float* tbase = tmat + (size_t)b * S_ * D_;
    for (int kt = 0; kt < 8; ++kt) {
        int k0 = kt * 64;
        __syncthreads();
#pragma unroll
        for (int j = 0; j < 2; ++j) {
            int f4 = t + j * 128;
            int r = f4 >> 4, c4 = (f4 & 15) * 4;
            *reinterpret_cast<float4*>(&As[r][c4]) =
                *reinterpret_cast<const float4*>(&abase[(size_t)r * S_ + k0 + c4]);
        }
#pragma unroll
        for (int j = 0; j < 8; ++j) {
            int f4 = t + j * 128;
            int r = f4 >> 4, c4 = (f4 & 15) * 4;
            *reinterpret_cast<float4*>(&Ts[r][c4]) =
                *reinterpret_cast<const float4*>(&tbase[(k0 + r) * D_ + c4]);
        }
        __syncthreads();
#pragma unroll
        for (int kc = 0; kc < 16; ++kc) {
            f32x4 tv[4];
#pragma unroll
            for (int ks = 0; ks < 4; ++ks)
                tv[ks] = *reinterpret_cast<f32x4*>(&Ts[kc * 4 + ks][dh * 4]);
#pragma unroll
            for (int i = 0; i < 2; ++i) {
                f32x4 av = *reinterpret_cast<f32x4*>(&As[qg * 2 + i][kc * 4]);
#pragma unroll
                for (int ks = 0; ks < 4; ++ks) acc[i] += av[ks] * tv[ks];
            }
        }
    }
#pragma unroll
    for (int i = 0; i < 2; ++i) {
        int row = b * S_ + q0 + qg * 2 + i;
        float inv = invs[row];
        size_t rowbase = (size_t)row * D_ + dh * 4;
        if (BF16OUT) {
            ushort4 r;
            r.x = f2bf(inv * acc[i][0]); r.y = f2bf(inv * acc[i][1]);
            r.z = f2bf(inv * acc[i][2]); r.w = f2bf(inv * acc[i][3]);
            *reinterpret_cast<ushort4*>(&outb[rowbase]) = r;
        } else {
            *reinterpret_cast<float4*>(&outf[rowbase]) =
                make_float4(inv * acc[i][0], inv * acc[i][1],
                            inv * acc[i][2], inv * acc[i][3]);
        }
    }
}

// ---------------- f32 -> bf16 cast (out_w) ----------------
__global__ __launch_bounds__(256) void cast_kernel(const float* __restrict__ in,
                                                   unsigned short* __restrict__ out, int n) {
    int i = (blockIdx.x * 256 + threadIdx.x) * 4;
    if (i >= n) return;
    float4 v = *reinterpret_cast<const float4*>(in + i);
    ushort4 r;
    r.x = f2bf(v.x); r.y = f2bf(v.y); r.z = f2bf(v.z); r.w = f2bf(v.w);
    *reinterpret_cast<ushort4*>(out + i) = r;
}

// ---------------- logits: out[8192,32000] = h2 @ out_w^T  (bf16 MFMA) ----------------
// 128 rows x 256 cols per block (8000 blocks = 64 mt x 125 nt). Streaming per-16-rows.
// Epilogue: dbuf 16x256 LDS stage, drain 1 row x 1024B contiguous per store instr.
// SINGLE barrier per iter (dbuf spans the WAR hazard across two barriers).
__global__ __launch_bounds__(256) void logits_kernel(const unsigned short* __restrict__ hb,
                                                     const unsigned short* __restrict__ wb,
                                                     float* __restrict__ out) {
    __shared__ float Ct[2][16][260];
    int bid = blockIdx.x;
    int nt = bid % 125, mt = bid / 125;
    int n0 = nt * 256, m0 = mt * 128;
    int wave = threadIdx.x >> 6, lane = threadIdx.x & 63;
    int lr = lane & 15, lh = lane >> 4;

    // a[c][ns][kh]: wb rows n0 + wave*64 + c*32 + ns*16 + lr
    bf16x8 a[2][2][2];
#pragma unroll
    for (int c = 0; c < 2; ++c)
#pragma unroll
        for (int ns = 0; ns < 2; ++ns)
#pragma unroll
            for (int kh = 0; kh < 2; ++kh)
                a[c][ns][kh] = *reinterpret_cast<const bf16x8*>(
                    wb + (size_t)(n0 + wave * 64 + c * 32 + ns * 16 + lr) * D_ + kh * 32 + lh * 8);

    for (int ms = 0; ms < 8; ++ms) {
        const unsigned short* hrow = hb + (size_t)(m0 + ms * 16 + lr) * D_ + lh * 8;
        bf16x8 b0 = *reinterpret_cast<const bf16x8*>(hrow);
        bf16x8 b1 = *reinterpret_cast<const bf16x8*>(hrow + 32);
        f32x4 acc[2][2];
#pragma unroll
        for (int c = 0; c < 2; ++c)
#pragma unroll
            for (int ns = 0; ns < 2; ++ns) {
                acc[c][ns] = (f32x4){0.f, 0.f, 0.f, 0.f};
                acc[c][ns] = __builtin_amdgcn_mfma_f32_16x16x32_bf16(a[c][ns][0], b0, acc[c][ns], 0, 0, 0);
                acc[c][ns] = __builtin_amdgcn_mfma_f32_16x16x32_bf16(a[c][ns][1], b1, acc[c][ns], 0, 0, 0);
            }

        // stage: row lr, cols wave*64 + c*32 + ns*16 + lh*4  (16B-aligned)
        float* Lw = &Ct[ms & 1][lr][wave * 64];
#pragma unroll
        for (int c = 0; c < 2; ++c)
#pragma unroll
            for (int ns = 0; ns < 2; ++ns) {
                f32x4 v = acc[c][ns];
                *reinterpret_cast<float4*>(Lw + c * 32 + ns * 16 + lh * 4) =
                    make_float4(v[0], v[1], v[2], v[3]);
            }
        __syncthreads();

        // drain: per instr, one full row x 1024B contiguous (64 lanes x 16B)
#pragma unroll
        for (int j = 0; j < 4; ++j) {
            int row = wave * 4 + j;
            const float* Lr = &Ct[ms & 1][row][lane * 4];
            float4 v = *reinterpret_cast<const float4*>(Lr);
            *reinterpret_cast<float4*>(out + (size_t)(m0 + ms * 16 + row) * V_ + n0 + lane * 4) = v;
        }
        // no trailing barrier: dbuf — iter i's drain[cur] is ordered before
        // iter i+2's stage[cur] by the single barrier in iter i+1.
    }
}

extern "C" void kernel_launch(void* const* d_in, const int* in_sizes, int n_in,
                              void* d_out, int out_size, void* d_ws, size_t ws_size,
                              hipStream_t stream) {
    const int*   tokens = (const int*)d_in[0];
    const float* temb   = (const float*)d_in[1];
    const float* w1     = (const float*)d_in[2];
    const float* w2     = (const float*)d_in[3];
    const float* escale = (const float*)d_in[4];
    const float* outw   = (const float*)d_in[5];
    float*       out    = (float*)d_out;

    // Large scratch in tail of d_out (1,048,576,000 B); consumed before logits.
    char* tail = (char*)d_out + 1048576000ull - 23068672ull;
    float* attn = (float*)(tail);                   // 16 MB (unnormalized exp)
    float* emb  = (float*)(tail + 16777216);        // 2 MB
    float* t1   = (float*)(tail + 18874368);        // 2 MB
    float* h1   = (float*)(tail + 20971520);        // 2 MB (ends at out end)

    // Small scratch in d_ws (~5.25 MB).
    char* ws = (char*)d_ws;
    unsigned short* hb   = (unsigned short*)(ws);             // 1 MB
    unsigned short* wb   = (unsigned short*)(ws + 1048576);   // 4 MB
    float*          n2   = (float*)(ws + 5144576);            // 32 KB
    float*          invs = (float*)(ws + 5177344);            // 32 KB

    embed_kernel<<<2048, 256, 0, stream>>>(tokens, temb, emb, n2);
    attn_kernel<<<512, 128, 0, stream>>>(emb, n2, escale, attn, invs);
    cast_kernel<<<2000, 256, 0, stream>>>(outw, wb, V_ * D_);
    proj_kernel<<<512, 256, 0, stream>>>(emb, w1, t1);
    prop_kernel<false><<<512, 128, 0, stream>>>(attn, t1, invs, h1, nullptr);
    proj_kernel<<<512, 256, 0, stream>>>(h1, w2, t1);
    prop_kernel<true><<<512, 128, 0, stream>>>(attn, t1, invs, nullptr, hb);
    logits_kernel<<<8000, 256, 0, stream>>>(hb, wb, out);
}